// Round 13
// baseline (4513.618 us; speedup 1.0000x reference)
//
#include <hip/hip_runtime.h>
#include <hip/hip_bf16.h>

#define VOCAB 32000
#define EMB   128
#define HID   256
#define G4H   1024
#define BS    8
#define SEQ   1024
#define NWG   8

typedef __attribute__((ext_vector_type(8))) short short8;
typedef __attribute__((ext_vector_type(4))) float f32x4;
typedef __attribute__((ext_vector_type(2))) int   i32x2;
typedef __attribute__((ext_vector_type(4))) int   i32x4;

static __device__ __forceinline__ unsigned short f2bf(float x) {
  union { __hip_bfloat16 b; unsigned short u; } cv;
  cv.b = __float2bfloat16(x);
  return cv.u;
}
static __device__ __forceinline__ float bf2f(unsigned short u) {
  union { unsigned short u; __hip_bfloat16 b; } cv;
  cv.u = u;
  return __bfloat162float(cv.b);
}
static __device__ __forceinline__ float fsigmoid(float x) {
  return 1.f / (1.f + __expf(-x));
}
static __device__ __forceinline__ float ftanh(float x) {
  return 2.f / (1.f + __expf(-2.f * x)) - 1.f;
}

static __device__ __forceinline__ i32x4 ld16t_cc(const unsigned short* p) {
  i32x4 r;
  asm volatile("global_load_dwordx4 %0, %1, off sc0 sc1" : "=v"(r) : "v"(p) : "memory");
  return r;
}
static __device__ __forceinline__ void st16_cc(unsigned short* p, i32x4 v) {
  asm volatile("global_store_dwordx4 %0, %1, off sc0 sc1" :: "v"(p), "v"(v) : "memory");
}
static __device__ __forceinline__ void st8_cc(unsigned short* p, i32x2 v) {
  asm volatile("global_store_dwordx2 %0, %1, off sc0 sc1" :: "v"(p), "v"(v) : "memory");
}

// ---------------- Kernel 1: embedding gather + x@W + bias -> xW (f32, in d_out)
__global__ __launch_bounds__(256) void k_embed_xw(
    const int* __restrict__ sent, const float* __restrict__ wemb,
    const float* __restrict__ W, const float* __restrict__ bias,
    float* __restrict__ xW) {
  int tid = threadIdx.x;
  int blk = blockIdx.x;
  int b  = blk >> 8;
  int t0 = (blk & 255) << 2;
  __shared__ float xs[4][EMB];
  #pragma unroll
  for (int i = 0; i < 2; ++i) {
    int flat = tid + (i << 8);
    int r = flat >> 7, e = flat & 127;
    int idx = sent[b * SEQ + t0 + r];
    xs[r][e] = wemb[idx * EMB + e];
  }
  __syncthreads();
  int g0 = tid << 2;
  float acc[4][4] = {};
  for (int e = 0; e < EMB; ++e) {
    float4 w4 = *(const float4*)&W[e * G4H + g0];
    #pragma unroll
    for (int r = 0; r < 4; ++r) {
      float xv = xs[r][e];
      acc[r][0] += xv * w4.x; acc[r][1] += xv * w4.y;
      acc[r][2] += xv * w4.z; acc[r][3] += xv * w4.w;
    }
  }
  float4 bi = *(const float4*)&bias[g0];
  #pragma unroll
  for (int r = 0; r < 4; ++r) {
    float4 o;
    o.x = acc[r][0] + bi.x; o.y = acc[r][1] + bi.y;
    o.z = acc[r][2] + bi.z; o.w = acc[r][3] + bi.w;
    *(float4*)&xW[(size_t)(b * SEQ + t0 + r) * G4H + g0] = o;
  }
}

// ---------------- Kernel 2: w_linear (256 x 32000 f32) -> BT (32000 x 256 bf16)
__global__ __launch_bounds__(256) void k_transpose_w(
    const float* __restrict__ w, unsigned short* __restrict__ BT) {
  __shared__ unsigned short tile[64][66];
  int n0 = blockIdx.x * 64, k0 = blockIdx.y * 64;
  int tid = threadIdx.x;
  #pragma unroll
  for (int i = 0; i < 16; ++i) {
    int flat = tid + i * 256;
    int kk = flat >> 6, nn = flat & 63;
    tile[kk][nn] = f2bf(w[(size_t)(k0 + kk) * VOCAB + n0 + nn]);
  }
  __syncthreads();
  #pragma unroll
  for (int i = 0; i < 16; ++i) {
    int flat = tid + i * 256;
    int nn = flat >> 6, kk = flat & 63;
    BT[(size_t)(n0 + nn) * HID + k0 + kk] = tile[kk][nn];
  }
}

// ---------------- Kernel 3: persistent LSTM scan — flagless tagged dataflow.
// 64 fully-symmetric waves (8 WGs x 512). Wave Wv owns hidden [Wv*4,Wv*4+4)
// for all 4 gates (column-permuted U). Record per (Wv,bat): 16B dwordx4 =
// {h0..h3 hi | lo0..lo2 | tag=t+1} — data and flag travel in ONE store.
// Readers poll their own 16 record loads and validate tags: the successful
// load IS the sync (1 LLC RT per step). No flags, no drains, no barriers.
// WAR-safe (R3 proof): storing step t requires having seen all step t-1 tags,
// which proves all waves finished reading the buffer being overwritten.
__global__ __launch_bounds__(512) void k_scan(
    const float* __restrict__ xW, const float* __restrict__ U,
    unsigned short* __restrict__ hidden,   // [8192][256] bf16
    unsigned short* __restrict__ rbuf) {   // [2][32 kq][8 bat][2 w][8 shorts]
  const int tid = threadIdx.x;
  const int l = tid & 63, v = tid >> 6;
  const int Wv = blockIdx.x * 8 + v;       // global wave id 0..63

  // persistent U B-fragments (split bf16 hi/lo); wave's 16 cols:
  // c16 = hid_local*4 + gate  ->  U column = gate*HID + Wv*4 + hid_local
  const int c16 = l & 15;
  const int colU = (c16 & 3) * HID + Wv * 4 + (c16 >> 2);
  short8 bhi[8], blo[8];
  #pragma unroll
  for (int kb = 0; kb < 8; ++kb) {
    #pragma unroll
    for (int j = 0; j < 8; ++j) {
      int k = kb * 32 + (l >> 4) * 8 + j;
      float uv = U[k * G4H + colU];
      unsigned short h16 = f2bf(uv);
      bhi[kb][j] = (short)h16;
      blo[kb][j] = (short)f2bf(uv - bf2f(h16));
    }
  }

  // gate-phase mapping (lanes 0..31): one (hidden unit, batch) each
  const int bat = l & 7;
  const int hl  = (l >> 3) & 3;
  const int H   = Wv * 4 + hl;

  __shared__ float xh[8][4][16][4];             // per-wave C transpose
  __shared__ unsigned short hp[8][8][4];        // per-wave h_hi staging
  __shared__ unsigned short lp[8][8][4];        // per-wave h_lo staging

  float xwp[4];
  if (l < 32) {
    #pragma unroll
    for (int g = 0; g < 4; ++g)
      xwp[g] = xW[((size_t)bat * SEQ + 0) * G4H + g * HID + H];
  }

  float c = 0.f;
  for (int t = 0; t < SEQ; ++t) {
    float sg[4] = {0.f, 0.f, 0.f, 0.f};
    if (t > 0) {
      const unsigned short* rb = rbuf + ((t - 1) & 1) * 4096;
      i32x4 r0[8], r1[8];
      const unsigned tagu = (unsigned)t;
      int guard = 0;
      for (;;) {
        #pragma unroll
        for (int kb = 0; kb < 8; ++kb) {
          int kq = kb * 4 + (l >> 4);
          const unsigned short* p = rb + (kq * 8 + (l & 7)) * 16;
          r0[kb] = ld16t_cc(p);
          r1[kb] = ld16t_cc(p + 8);
        }
        asm volatile("s_waitcnt vmcnt(0)" ::: "memory");
        __builtin_amdgcn_sched_barrier(0);
        bool ok = true;
        #pragma unroll
        for (int kb = 0; kb < 8; ++kb)
          ok = ok && (((unsigned)r0[kb].w >> 16) == tagu) &&
                     (((unsigned)r1[kb].w >> 16) == tagu);
        if (__all(ok)) break;
        if (++guard > 20000) break;             // anti-deadlock bailout
      }
      // unpack: ah = hi dwords; al = lo dwords with tag halves zeroed
      short8 ah[8], al[8];
      #pragma unroll
      for (int kb = 0; kb < 8; ++kb) {
        union RU { i32x4 i; short8 s; } uh, ul;
        uh.i.x = r0[kb].x; uh.i.y = r0[kb].y;
        uh.i.z = r1[kb].x; uh.i.w = r1[kb].y;
        ul.i.x = r0[kb].z; ul.i.y = r0[kb].w & 0xffff;
        ul.i.z = r1[kb].z; ul.i.w = r1[kb].w & 0xffff;
        ah[kb] = uh.s; al[kb] = ul.s;
      }
      // 3 independent MFMA chains (depth 8 each), summed
      f32x4 a1 = {0.f, 0.f, 0.f, 0.f};
      f32x4 a2 = {0.f, 0.f, 0.f, 0.f};
      f32x4 a3 = {0.f, 0.f, 0.f, 0.f};
      #pragma unroll
      for (int kb = 0; kb < 8; ++kb) {
        a1 = __builtin_amdgcn_mfma_f32_16x16x32_bf16(ah[kb], bhi[kb], a1, 0, 0, 0);
        a2 = __builtin_amdgcn_mfma_f32_16x16x32_bf16(ah[kb], blo[kb], a2, 0, 0, 0);
        a3 = __builtin_amdgcn_mfma_f32_16x16x32_bf16(al[kb], bhi[kb], a3, 0, 0, 0);
      }
      f32x4 acc = a1 + a2 + a3;
      // intra-wave C transpose through LDS (same wave: lgkm wait only)
      *(f32x4*)&xh[v][l >> 4][c16][0] = acc;
      asm volatile("s_waitcnt lgkmcnt(0)" ::: "memory");
      __builtin_amdgcn_sched_barrier(0);
      if (l < 32) {
        #pragma unroll
        for (int g = 0; g < 4; ++g)
          sg[g] = xh[v][bat >> 2][hl * 4 + g][bat & 3];
      }
    }

    if (l < 32) {
      float iv = fsigmoid(sg[0] + xwp[0]);
      float fv = fsigmoid(sg[1] + xwp[1]);
      float gv = ftanh   (sg[2] + xwp[2]);
      float ov = fsigmoid(sg[3] + xwp[3]);
      c = fv * c + iv * gv;
      float h = ov * ftanh(c);
      unsigned short hhi = f2bf(h);
      hp[v][bat][hl] = hhi;
      lp[v][bat][hl] = f2bf(h - bf2f(hhi));
    }
    asm volatile("s_waitcnt lgkmcnt(0)" ::: "memory");
    __builtin_amdgcn_sched_barrier(0);
    if (l < 8) {
      unsigned h0 = hp[v][l][0], h1 = hp[v][l][1], h2 = hp[v][l][2], h3 = hp[v][l][3];
      unsigned o0 = lp[v][l][0], o1 = lp[v][l][1], o2 = lp[v][l][2];
      i32x4 rec;
      rec.x = (int)((h1 << 16) | h0);
      rec.y = (int)((h3 << 16) | h2);
      rec.z = (int)((o1 << 16) | o0);
      rec.w = (int)((((unsigned)(t + 1)) << 16) | o2);
      unsigned short* dst =
          rbuf + (t & 1) * 4096 + (((Wv >> 1) * 8 + l) * 2 + (Wv & 1)) * 8;
      st16_cc(dst, rec);                        // data + tag, ONE store
      // off-critical-path: hidden row segment (4 hi values)
      i32x2 hv; hv.x = rec.x; hv.y = rec.y;
      st8_cc(hidden + ((size_t)l * SEQ + t) * HID + Wv * 4, hv);
    }
    // prefetch next step's xW (in flight during peers' compute)
    if (l < 32) {
      int tn = (t + 1 < SEQ) ? t + 1 : t;
      #pragma unroll
      for (int g = 0; g < 4; ++g)
        xwp[g] = xW[((size_t)bat * SEQ + tn) * G4H + g * HID + H];
    }
  }
}

// ---------------- Kernel 4: hidden @ w_linear^T + bias -> out (bf16 MFMA, f32 out)
__global__ __launch_bounds__(256) void k_gemm_out(
    const unsigned short* __restrict__ A,   // [8192][256] bf16
    const unsigned short* __restrict__ BT,  // [32000][256] bf16
    const float* __restrict__ bias, float* __restrict__ C) {
  const int n0 = blockIdx.x * 128;
  const int m0 = blockIdx.y * 128;
  const int tid = threadIdx.x;
  const int l = tid & 63, wv = tid >> 6;
  const int wr = wv >> 1, wc = wv & 1;
  __shared__ unsigned short As[128 * 72];
  __shared__ unsigned short Bs[128 * 72];
  f32x4 acc[4][4] = {};
  const int r = tid >> 1, seg = tid & 1;
  for (int kt = 0; kt < 4; ++kt) {
    int k0 = kt * 64;
    #pragma unroll
    for (int i = 0; i < 4; ++i) {
      *(short8*)&As[r * 72 + seg * 32 + i * 8] =
          *(const short8*)&A[(size_t)(m0 + r) * HID + k0 + seg * 32 + i * 8];
      *(short8*)&Bs[r * 72 + seg * 32 + i * 8] =
          *(const short8*)&BT[(size_t)(n0 + r) * HID + k0 + seg * 32 + i * 8];
    }
    __syncthreads();
    #pragma unroll
    for (int kb = 0; kb < 2; ++kb) {
      short8 af[4], bf[4];
      #pragma unroll
      for (int mi = 0; mi < 4; ++mi)
        af[mi] = *(const short8*)&As[(wr * 64 + mi * 16 + (l & 15)) * 72 +
                                     kb * 32 + (l >> 4) * 8];
      #pragma unroll
      for (int ni = 0; ni < 4; ++ni)
        bf[ni] = *(const short8*)&Bs[(wc * 64 + ni * 16 + (l & 15)) * 72 +
                                     kb * 32 + (l >> 4) * 8];
      #pragma unroll
      for (int mi = 0; mi < 4; ++mi)
        #pragma unroll
        for (int ni = 0; ni < 4; ++ni)
          acc[mi][ni] = __builtin_amdgcn_mfma_f32_16x16x32_bf16(
              af[mi], bf[ni], acc[mi][ni], 0, 0, 0);
    }
    __syncthreads();
  }
  #pragma unroll
  for (int ni = 0; ni < 4; ++ni) {
    int n = n0 + wc * 64 + ni * 16 + (l & 15);
    float bi = bias[n];
    #pragma unroll
    for (int mi = 0; mi < 4; ++mi) {
      int mbase = m0 + wr * 64 + mi * 16 + (l >> 4) * 4;
      #pragma unroll
      for (int q = 0; q < 4; ++q)
        C[(size_t)(mbase + q) * VOCAB + n] = acc[mi][ni][q] + bi;
    }
  }
}

extern "C" void kernel_launch(void* const* d_in, const int* in_sizes, int n_in,
                              void* d_out, int out_size, void* d_ws, size_t ws_size,
                              hipStream_t stream) {
  const int*   sent = (const int*)d_in[0];
  const float* wemb = (const float*)d_in[1];
  const float* W    = (const float*)d_in[2];
  const float* U    = (const float*)d_in[3];
  const float* bias = (const float*)d_in[4];
  const float* wlin = (const float*)d_in[5];
  const float* blin = (const float*)d_in[6];
  float* out = (float*)d_out;

  // xW (32 MB f32) lives in d_out scratch; GEMM overwrites all of d_out later.
  float* xW = out;

  char* ws = (char*)d_ws;
  unsigned short* BT     = (unsigned short*)ws;                    // 16,384,000 B
  unsigned short* hidden = (unsigned short*)(ws + 16384000);       //  4,194,304 B
  unsigned short* rbuf   = (unsigned short*)(ws + 16384000 + 4194304);  // 16,384 B

  hipMemsetAsync(rbuf, 0, 16384, stream);           // tags := 0 (never match)
  k_embed_xw<<<2048, 256, 0, stream>>>(sent, wemb, W, bias, xW);
  k_transpose_w<<<dim3(500, 4), 256, 0, stream>>>(wlin, BT);
  k_scan<<<NWG, 512, 0, stream>>>(xW, U, hidden, rbuf);
  k_gemm_out<<<dim3(250, 64), 256, 0, stream>>>(hidden, BT, blin, out);
}

// Round 14
// 3254.325 us; speedup vs baseline: 1.3870x; 1.3870x over previous
//
#include <hip/hip_runtime.h>
#include <hip/hip_bf16.h>

#define VOCAB 32000
#define EMB   128
#define HID   256
#define G4H   1024
#define BS    8
#define SEQ   1024
#define NWG   8

typedef __attribute__((ext_vector_type(8))) short short8;
typedef __attribute__((ext_vector_type(4))) float f32x4;
typedef __attribute__((ext_vector_type(2))) int   i32x2;

static __device__ __forceinline__ unsigned short f2bf(float x) {
  union { __hip_bfloat16 b; unsigned short u; } cv;
  cv.b = __float2bfloat16(x);
  return cv.u;
}
static __device__ __forceinline__ float bf2f(unsigned short u) {
  union { unsigned short u; __hip_bfloat16 b; } cv;
  cv.u = u;
  return __bfloat162float(cv.b);
}
static __device__ __forceinline__ float fsigmoid(float x) {
  return 1.f / (1.f + __expf(-x));
}
static __device__ __forceinline__ float ftanh(float x) {
  return 2.f / (1.f + __expf(-2.f * x)) - 1.f;
}

// ---- LLC-direct helpers (coherence point; no cache maintenance).
static __device__ __forceinline__ int ld_int_cc(const int* p) {
  int r;
  asm volatile("global_load_dword %0, %1, off sc0 sc1\n\ts_waitcnt vmcnt(0)"
               : "=v"(r) : "v"(p) : "memory");
  return r;
}
static __device__ __forceinline__ void st_int_cc(int* p, int v) {
  asm volatile("global_store_dword %0, %1, off sc0 sc1" :: "v"(p), "v"(v) : "memory");
}
static __device__ __forceinline__ short8 ld16_cc(const unsigned short* p) {
  short8 r;
  asm volatile("global_load_dwordx4 %0, %1, off sc0 sc1" : "=v"(r) : "v"(p) : "memory");
  return r;
}
static __device__ __forceinline__ void st8_cc(unsigned short* p, i32x2 v) {
  asm volatile("global_store_dwordx2 %0, %1, off sc0 sc1" :: "v"(p), "v"(v) : "memory");
}
static __device__ __forceinline__ void st_f32_nt(float* p, float v) {
  asm volatile("global_store_dword %0, %1, off nt" :: "v"(p), "v"(v) : "memory");
}

// ---------------- Kernel 1: embedding gather + x@W + bias -> xW (f32, d_out tail)
__global__ __launch_bounds__(256) void k_embed_xw(
    const int* __restrict__ sent, const float* __restrict__ wemb,
    const float* __restrict__ W, const float* __restrict__ bias,
    float* __restrict__ xW) {
  int tid = threadIdx.x;
  int blk = blockIdx.x;
  int b  = blk >> 8;
  int t0 = (blk & 255) << 2;
  __shared__ float xs[4][EMB];
  #pragma unroll
  for (int i = 0; i < 2; ++i) {
    int flat = tid + (i << 8);
    int r = flat >> 7, e = flat & 127;
    int idx = sent[b * SEQ + t0 + r];
    xs[r][e] = wemb[idx * EMB + e];
  }
  __syncthreads();
  int g0 = tid << 2;
  float acc[4][4] = {};
  for (int e = 0; e < EMB; ++e) {
    float4 w4 = *(const float4*)&W[e * G4H + g0];
    #pragma unroll
    for (int r = 0; r < 4; ++r) {
      float xv = xs[r][e];
      acc[r][0] += xv * w4.x; acc[r][1] += xv * w4.y;
      acc[r][2] += xv * w4.z; acc[r][3] += xv * w4.w;
    }
  }
  float4 bi = *(const float4*)&bias[g0];
  #pragma unroll
  for (int r = 0; r < 4; ++r) {
    float4 o;
    o.x = acc[r][0] + bi.x; o.y = acc[r][1] + bi.y;
    o.z = acc[r][2] + bi.z; o.w = acc[r][3] + bi.w;
    *(float4*)&xW[(size_t)(b * SEQ + t0 + r) * G4H + g0] = o;
  }
}

// ---------------- Kernel 2: w_linear (256 x 32000 f32) -> BT (32000 x 256 bf16)
__global__ __launch_bounds__(256) void k_transpose_w(
    const float* __restrict__ w, unsigned short* __restrict__ BT) {
  __shared__ unsigned short tile[64][66];
  int n0 = blockIdx.x * 64, k0 = blockIdx.y * 64;
  int tid = threadIdx.x;
  #pragma unroll
  for (int i = 0; i < 16; ++i) {
    int flat = tid + i * 256;
    int kk = flat >> 6, nn = flat & 63;
    tile[kk][nn] = f2bf(w[(size_t)(k0 + kk) * VOCAB + n0 + nn]);
  }
  __syncthreads();
  #pragma unroll
  for (int i = 0; i < 16; ++i) {
    int flat = tid + i * 256;
    int nn = flat >> 6, kk = flat & 63;
    BT[(size_t)(n0 + nn) * HID + k0 + kk] = tile[kk][nn];
  }
}

// ---------------- Kernel 3: FUSED scan (R8 core) + progress-gated 256x256 GEMM.
// LDS padded to 96 KB -> ONE block per CU (scan WGs own their CUs). 256-row
// M-tiles halve B-panel LLC re-reads (less interference with the scan's LLC
// sync chain). prog far from flags, published every 16 steps; slow pollers.
struct ScanS {
  float xh[8][4][16][4];
  unsigned short hp[8][8][4];
  unsigned short lp[8][8][4];
};
struct GemmS {
  unsigned short As[256 * 72];
  unsigned short Bs[256 * 72];
};
union SMem { ScanS s; GemmS g; char pad[98304]; };

__global__ __launch_bounds__(512) void k_fused(
    const float* __restrict__ xW, const float* __restrict__ U,
    unsigned short* __restrict__ hidden,   // [8192][256] bf16 (ws)
    unsigned short* __restrict__ hbuf,     // [2][32 kq][8 bat][8 j] hi
    unsigned short* __restrict__ lbuf,     // [2][32 kq][8 bat][8 j] lo
    int* __restrict__ flags,               // [8] per-WG step counters (1 line)
    int* __restrict__ prog,                // [8*32] progress, 8 lines, far away
    const unsigned short* __restrict__ BT, // [32000][256] bf16
    const float* __restrict__ blin,
    float* __restrict__ C) {
  __shared__ SMem sm;
  const int bx = blockIdx.x;
  const int tid = threadIdx.x;
  const int l = tid & 63, v = tid >> 6;

  if (bx < NWG) {
    // ================= SCAN (R8 core, verbatim) =================
    const int w = bx;
    const int Wv = w * 8 + v;

    const int c16 = l & 15;
    const int colU = (c16 & 3) * HID + Wv * 4 + (c16 >> 2);
    short8 bhi[8], blo[8];
    #pragma unroll
    for (int kb = 0; kb < 8; ++kb) {
      #pragma unroll
      for (int j = 0; j < 8; ++j) {
        int k = kb * 32 + (l >> 4) * 8 + j;
        float uv = U[k * G4H + colU];
        unsigned short h16 = f2bf(uv);
        bhi[kb][j] = (short)h16;
        blo[kb][j] = (short)f2bf(uv - bf2f(h16));
      }
    }

    const int bat = l & 7;
    const int hl  = (l >> 3) & 3;
    const int H   = Wv * 4 + hl;

    float xwp[4];
    if (l < 32) {
      #pragma unroll
      for (int g = 0; g < 4; ++g)
        xwp[g] = xW[((size_t)bat * SEQ + 0) * G4H + g * HID + H];
    }

    float c = 0.f;
    for (int t = 0; t < SEQ; ++t) {
      float sg[4] = {0.f, 0.f, 0.f, 0.f};
      if (t > 0) {
        if (v == 0) {
          const int* fp = &flags[l & 7];
          int guard = 0;
          for (;;) {
            int f = ld_int_cc(fp);
            if (__all(f >= t)) break;
            if (++guard > 30000) break;
          }
          if (w == 0 && l < 8 && (t & 15) == 0) st_int_cc(&prog[l * 32], t);
        }
        __syncthreads();                        // barrier A

        const unsigned short* hb = hbuf + ((t - 1) & 1) * 2048;
        const unsigned short* lb = lbuf + ((t - 1) & 1) * 2048;
        short8 ah[8], al[8];
        #pragma unroll
        for (int kb = 0; kb < 8; ++kb) {
          int off = ((kb * 4 + (l >> 4)) * 8 + (l & 7)) * 8;
          ah[kb] = ld16_cc(hb + off);
          al[kb] = ld16_cc(lb + off);
        }
        asm volatile("s_waitcnt vmcnt(0)" ::: "memory");
        __builtin_amdgcn_sched_barrier(0);
        f32x4 a1 = {0.f, 0.f, 0.f, 0.f};
        f32x4 a2 = {0.f, 0.f, 0.f, 0.f};
        f32x4 a3 = {0.f, 0.f, 0.f, 0.f};
        #pragma unroll
        for (int kb = 0; kb < 8; ++kb) {
          a1 = __builtin_amdgcn_mfma_f32_16x16x32_bf16(ah[kb], bhi[kb], a1, 0, 0, 0);
          a2 = __builtin_amdgcn_mfma_f32_16x16x32_bf16(ah[kb], blo[kb], a2, 0, 0, 0);
          a3 = __builtin_amdgcn_mfma_f32_16x16x32_bf16(al[kb], bhi[kb], a3, 0, 0, 0);
        }
        f32x4 acc = a1 + a2 + a3;
        *(f32x4*)&sm.s.xh[v][l >> 4][c16][0] = acc;
        asm volatile("s_waitcnt lgkmcnt(0)" ::: "memory");
        __builtin_amdgcn_sched_barrier(0);
        if (l < 32) {
          #pragma unroll
          for (int g = 0; g < 4; ++g)
            sg[g] = sm.s.xh[v][bat >> 2][hl * 4 + g][bat & 3];
        }
      }

      if (l < 32) {
        float iv = fsigmoid(sg[0] + xwp[0]);
        float fv = fsigmoid(sg[1] + xwp[1]);
        float gv = ftanh   (sg[2] + xwp[2]);
        float ov = fsigmoid(sg[3] + xwp[3]);
        c = fv * c + iv * gv;
        float h = ov * ftanh(c);
        unsigned short hhi = f2bf(h);
        sm.s.hp[v][bat][hl] = hhi;
        sm.s.lp[v][bat][hl] = f2bf(h - bf2f(hhi));
      }
      asm volatile("s_waitcnt lgkmcnt(0)" ::: "memory");
      __builtin_amdgcn_sched_barrier(0);
      if (l < 8) {
        unsigned h0 = sm.s.hp[v][l][0], h1 = sm.s.hp[v][l][1];
        unsigned h2 = sm.s.hp[v][l][2], h3 = sm.s.hp[v][l][3];
        unsigned o0 = sm.s.lp[v][l][0], o1 = sm.s.lp[v][l][1];
        unsigned o2 = sm.s.lp[v][l][2], o3 = sm.s.lp[v][l][3];
        i32x2 rh, rl;
        rh.x = (int)((h1 << 16) | h0); rh.y = (int)((h3 << 16) | h2);
        rl.x = (int)((o1 << 16) | o0); rl.y = (int)((o3 << 16) | o2);
        int off = ((Wv >> 1) * 8 + l) * 8 + (Wv & 1) * 4;
        st8_cc(hbuf + (t & 1) * 2048 + off, rh);
        st8_cc(lbuf + (t & 1) * 2048 + off, rl);
        // hidden row segment (bat=l, cols Wv*4..+3) -> LLC BEFORE drain
        st8_cc(hidden + ((size_t)l * SEQ + t) * HID + Wv * 4, rh);
      }
      asm volatile("s_waitcnt vmcnt(0)" ::: "memory");
      __syncthreads();                          // barrier B
      if (tid == 0) st_int_cc(&flags[w], t + 1);
      if (l < 32) {
        int tn = (t + 1 < SEQ) ? t + 1 : t;
        #pragma unroll
        for (int g = 0; g < 4; ++g)
          xwp[g] = xW[((size_t)bat * SEQ + tn) * G4H + g * HID + H];
      }
    }
    // final publish: prove all WGs finished all SEQ steps
    if (bx == 0 && v == 0) {
      const int* fp = &flags[l & 7];
      int guard = 0;
      for (;;) {
        int f = ld_int_cc(fp);
        if (__all(f >= SEQ)) break;
        if (++guard > 30000) break;
      }
      if (l < 8) st_int_cc(&prog[l * 32], SEQ);
    }
    return;
  }

  // ============ GEMM tile 256x256 (progress-gated), 8 waves 2x4 ============
  const int gb = bx - NWG;                 // 0..3999, t-major order
  int nb = gb % 125;
  int t2 = gb / 125;                       // 0..31
  int bat = t2 & 7, tblk = t2 >> 3;        // tblk 0..3
  int m0 = bat * 1024 + tblk * 256;
  int n0 = nb * 256;
  // xW lives in d_out tail (C rows >= 7930): wait for the full scan there
  int gate = (bat == 7 && tblk >= 2) ? SEQ : (tblk * 256 + 256);

  if (tid == 0) {
    const int* pp = &prog[(gb & 7) * 32];
    int guard = 0;
    while (ld_int_cc(pp) < gate) {
      #pragma unroll
      for (int s = 0; s < 4; ++s) __builtin_amdgcn_s_sleep(127);
      if (++guard > 4000) break;           // ~52 ms cap, way past scan end
    }
  }
  __syncthreads();

  const unsigned short* A = hidden;
  const int wr = v >> 2, wc = v & 3;       // wave -> 128x64 sub-tile
  f32x4 acc[8][4] = {};
  for (int kt = 0; kt < 4; ++kt) {
    int k0 = kt * 64;
    #pragma unroll
    for (int i = 0; i < 4; ++i) {
      int flat = tid + i * 512;
      int r = flat >> 3, cc = flat & 7;
      *(short8*)&sm.g.As[r * 72 + cc * 8] =
          *(const short8*)&A[(size_t)(m0 + r) * HID + k0 + cc * 8];
    }
    #pragma unroll
    for (int i = 0; i < 4; ++i) {
      int flat = tid + i * 512;
      int r = flat >> 3, cc = flat & 7;
      *(short8*)&sm.g.Bs[r * 72 + cc * 8] =
          *(const short8*)&BT[(size_t)(n0 + r) * HID + k0 + cc * 8];
    }
    __syncthreads();
    #pragma unroll
    for (int kb = 0; kb < 2; ++kb) {
      short8 af[8], bf[4];
      #pragma unroll
      for (int mi = 0; mi < 8; ++mi)
        af[mi] = *(const short8*)&sm.g.As[(wr * 128 + mi * 16 + (l & 15)) * 72 +
                                          kb * 32 + (l >> 4) * 8];
      #pragma unroll
      for (int ni = 0; ni < 4; ++ni)
        bf[ni] = *(const short8*)&sm.g.Bs[(wc * 64 + ni * 16 + (l & 15)) * 72 +
                                          kb * 32 + (l >> 4) * 8];
      #pragma unroll
      for (int mi = 0; mi < 8; ++mi)
        #pragma unroll
        for (int ni = 0; ni < 4; ++ni)
          acc[mi][ni] = __builtin_amdgcn_mfma_f32_16x16x32_bf16(
              af[mi], bf[ni], acc[mi][ni], 0, 0, 0);
    }
    __syncthreads();
  }
  #pragma unroll
  for (int ni = 0; ni < 4; ++ni) {
    int n = n0 + wc * 64 + ni * 16 + (l & 15);
    float bi = blin[n];
    #pragma unroll
    for (int mi = 0; mi < 8; ++mi) {
      int mbase = m0 + wr * 128 + mi * 16 + (l >> 4) * 4;
      #pragma unroll
      for (int q = 0; q < 4; ++q)
        st_f32_nt(&C[(size_t)(mbase + q) * VOCAB + n], acc[mi][ni][q] + bi);
    }
  }
}

extern "C" void kernel_launch(void* const* d_in, const int* in_sizes, int n_in,
                              void* d_out, int out_size, void* d_ws, size_t ws_size,
                              hipStream_t stream) {
  const int*   sent = (const int*)d_in[0];
  const float* wemb = (const float*)d_in[1];
  const float* W    = (const float*)d_in[2];
  const float* U    = (const float*)d_in[3];
  const float* bias = (const float*)d_in[4];
  const float* wlin = (const float*)d_in[5];
  const float* blin = (const float*)d_in[6];
  float* out = (float*)d_out;

  // xW (32 MB f32) at the TAIL of d_out; overlapping C rows gated at SEQ.
  float* xW = out + (262144000 - 8388608);

  char* ws = (char*)d_ws;
  unsigned short* BT     = (unsigned short*)ws;                        // 16,384,000 B
  unsigned short* hidden = (unsigned short*)(ws + 16384000);           //  4,194,304 B
  unsigned short* hbuf   = (unsigned short*)(ws + 16384000 + 4194304);           // 8 KB (pad 16K)
  unsigned short* lbuf   = (unsigned short*)(ws + 16384000 + 4194304 + 16384);   // 8 KB (pad 16K)
  int* flags             = (int*)(ws + 16384000 + 4194304 + 32768);              // 32 B
  int* prog              = (int*)(ws + 16384000 + 4194304 + 32768 + 131072);     // 1 KB, far away

  hipMemsetAsync(flags, 0, 64, stream);
  hipMemsetAsync(prog, 0, 1024, stream);
  k_embed_xw<<<2048, 256, 0, stream>>>(sent, wemb, W, bias, xW);
  k_transpose_w<<<dim3(500, 4), 256, 0, stream>>>(wlin, BT);
  k_fused<<<NWG + 4000, 512, 0, stream>>>(xW, U, hidden, hbuf, lbuf,
                                          flags, prog, BT, blin, out);
}

// Round 15
// 3169.584 us; speedup vs baseline: 1.4240x; 1.0267x over previous
//
#include <hip/hip_runtime.h>
#include <hip/hip_bf16.h>

#define VOCAB 32000
#define EMB   128
#define HID   256
#define G4H   1024
#define BS    8
#define SEQ   1024
#define NWG   8

typedef __attribute__((ext_vector_type(8))) short short8;
typedef __attribute__((ext_vector_type(4))) float f32x4;
typedef __attribute__((ext_vector_type(2))) int   i32x2;

static __device__ __forceinline__ unsigned short f2bf(float x) {
  union { __hip_bfloat16 b; unsigned short u; } cv;
  cv.b = __float2bfloat16(x);
  return cv.u;
}
static __device__ __forceinline__ float bf2f(unsigned short u) {
  union { unsigned short u; __hip_bfloat16 b; } cv;
  cv.u = u;
  return __bfloat162float(cv.b);
}
static __device__ __forceinline__ float fsigmoid(float x) {
  return 1.f / (1.f + __expf(-x));
}
static __device__ __forceinline__ float ftanh(float x) {
  return 2.f / (1.f + __expf(-2.f * x)) - 1.f;
}

// ---- LLC-direct helpers (coherence point; no cache maintenance).
static __device__ __forceinline__ int ld_int_cc(const int* p) {
  int r;
  asm volatile("global_load_dword %0, %1, off sc0 sc1\n\ts_waitcnt vmcnt(0)"
               : "=v"(r) : "v"(p) : "memory");
  return r;
}
static __device__ __forceinline__ void st_int_cc(int* p, int v) {
  asm volatile("global_store_dword %0, %1, off sc0 sc1" :: "v"(p), "v"(v) : "memory");
}
static __device__ __forceinline__ short8 ld16_cc(const unsigned short* p) {
  short8 r;
  asm volatile("global_load_dwordx4 %0, %1, off sc0 sc1" : "=v"(r) : "v"(p) : "memory");
  return r;
}
static __device__ __forceinline__ void st8_cc(unsigned short* p, i32x2 v) {
  asm volatile("global_store_dwordx2 %0, %1, off sc0 sc1" :: "v"(p), "v"(v) : "memory");
}
static __device__ __forceinline__ void st_f32_nt(float* p, float v) {
  asm volatile("global_store_dword %0, %1, off nt" :: "v"(p), "v"(v) : "memory");
}

// ---------------- Kernel 1: embedding gather + x@W + bias -> xW (f32, d_out tail)
__global__ __launch_bounds__(256) void k_embed_xw(
    const int* __restrict__ sent, const float* __restrict__ wemb,
    const float* __restrict__ W, const float* __restrict__ bias,
    float* __restrict__ xW) {
  int tid = threadIdx.x;
  int blk = blockIdx.x;
  int b  = blk >> 8;
  int t0 = (blk & 255) << 2;
  __shared__ float xs[4][EMB];
  #pragma unroll
  for (int i = 0; i < 2; ++i) {
    int flat = tid + (i << 8);
    int r = flat >> 7, e = flat & 127;
    int idx = sent[b * SEQ + t0 + r];
    xs[r][e] = wemb[idx * EMB + e];
  }
  __syncthreads();
  int g0 = tid << 2;
  float acc[4][4] = {};
  for (int e = 0; e < EMB; ++e) {
    float4 w4 = *(const float4*)&W[e * G4H + g0];
    #pragma unroll
    for (int r = 0; r < 4; ++r) {
      float xv = xs[r][e];
      acc[r][0] += xv * w4.x; acc[r][1] += xv * w4.y;
      acc[r][2] += xv * w4.z; acc[r][3] += xv * w4.w;
    }
  }
  float4 bi = *(const float4*)&bias[g0];
  #pragma unroll
  for (int r = 0; r < 4; ++r) {
    float4 o;
    o.x = acc[r][0] + bi.x; o.y = acc[r][1] + bi.y;
    o.z = acc[r][2] + bi.z; o.w = acc[r][3] + bi.w;
    *(float4*)&xW[(size_t)(b * SEQ + t0 + r) * G4H + g0] = o;
  }
}

// ---------------- Kernel 2: w_linear (256 x 32000 f32) -> BT (32000 x 256 bf16)
__global__ __launch_bounds__(256) void k_transpose_w(
    const float* __restrict__ w, unsigned short* __restrict__ BT) {
  __shared__ unsigned short tile[64][66];
  int n0 = blockIdx.x * 64, k0 = blockIdx.y * 64;
  int tid = threadIdx.x;
  #pragma unroll
  for (int i = 0; i < 16; ++i) {
    int flat = tid + i * 256;
    int kk = flat >> 6, nn = flat & 63;
    tile[kk][nn] = f2bf(w[(size_t)(k0 + kk) * VOCAB + n0 + nn]);
  }
  __syncthreads();
  #pragma unroll
  for (int i = 0; i < 16; ++i) {
    int flat = tid + i * 256;
    int nn = flat >> 6, kk = flat & 63;
    BT[(size_t)(n0 + nn) * HID + k0 + kk] = tile[kk][nn];
  }
}

// ---------------- Kernel 3: FUSED scan (R8 core) + progress-gated GEMM.
// LDS padded to 96 KB -> exactly ONE block per CU: scan WGs own their CUs
// (no issue-slot theft). prog 128 KB away from flags, published every 16
// steps; GEMM pollers sleep ~13 us/retry. C-stores are nt (no LLC churn).
struct ScanS {
  float xh[8][4][16][4];
  unsigned short hp[8][8][4];
  unsigned short lp[8][8][4];
};
struct GemmS {
  unsigned short As[128 * 72];
  unsigned short Bs[256 * 72];
};
union SMem { ScanS s; GemmS g; char pad[98304]; };

__global__ __launch_bounds__(512) void k_fused(
    const float* __restrict__ xW, const float* __restrict__ U,
    unsigned short* __restrict__ hidden,   // [8192][256] bf16 (ws)
    unsigned short* __restrict__ hbuf,     // [2][32 kq][8 bat][8 j] hi
    unsigned short* __restrict__ lbuf,     // [2][32 kq][8 bat][8 j] lo
    int* __restrict__ flags,               // [8] per-WG step counters (1 line)
    int* __restrict__ prog,                // [8*32] progress, 8 lines, far away
    const unsigned short* __restrict__ BT, // [32000][256] bf16
    const float* __restrict__ blin,
    float* __restrict__ C) {
  __shared__ SMem sm;
  const int bx = blockIdx.x;
  const int tid = threadIdx.x;
  const int l = tid & 63, v = tid >> 6;

  if (bx < NWG) {
    // ================= SCAN (R8 core, verbatim) =================
    const int w = bx;
    const int Wv = w * 8 + v;

    const int c16 = l & 15;
    const int colU = (c16 & 3) * HID + Wv * 4 + (c16 >> 2);
    short8 bhi[8], blo[8];
    #pragma unroll
    for (int kb = 0; kb < 8; ++kb) {
      #pragma unroll
      for (int j = 0; j < 8; ++j) {
        int k = kb * 32 + (l >> 4) * 8 + j;
        float uv = U[k * G4H + colU];
        unsigned short h16 = f2bf(uv);
        bhi[kb][j] = (short)h16;
        blo[kb][j] = (short)f2bf(uv - bf2f(h16));
      }
    }

    const int bat = l & 7;
    const int hl  = (l >> 3) & 3;
    const int H   = Wv * 4 + hl;

    float xwp[4];
    if (l < 32) {
      #pragma unroll
      for (int g = 0; g < 4; ++g)
        xwp[g] = xW[((size_t)bat * SEQ + 0) * G4H + g * HID + H];
    }

    float c = 0.f;
    for (int t = 0; t < SEQ; ++t) {
      float sg[4] = {0.f, 0.f, 0.f, 0.f};
      if (t > 0) {
        if (v == 0) {
          const int* fp = &flags[l & 7];
          int guard = 0;
          for (;;) {
            int f = ld_int_cc(fp);
            if (__all(f >= t)) break;
            if (++guard > 30000) break;
          }
          if (w == 0 && l < 8 && (t & 15) == 0) st_int_cc(&prog[l * 32], t);
        }
        __syncthreads();                        // barrier A

        const unsigned short* hb = hbuf + ((t - 1) & 1) * 2048;
        const unsigned short* lb = lbuf + ((t - 1) & 1) * 2048;
        short8 ah[8], al[8];
        #pragma unroll
        for (int kb = 0; kb < 8; ++kb) {
          int off = ((kb * 4 + (l >> 4)) * 8 + (l & 7)) * 8;
          ah[kb] = ld16_cc(hb + off);
          al[kb] = ld16_cc(lb + off);
        }
        asm volatile("s_waitcnt vmcnt(0)" ::: "memory");
        __builtin_amdgcn_sched_barrier(0);
        f32x4 a1 = {0.f, 0.f, 0.f, 0.f};
        f32x4 a2 = {0.f, 0.f, 0.f, 0.f};
        f32x4 a3 = {0.f, 0.f, 0.f, 0.f};
        #pragma unroll
        for (int kb = 0; kb < 8; ++kb) {
          a1 = __builtin_amdgcn_mfma_f32_16x16x32_bf16(ah[kb], bhi[kb], a1, 0, 0, 0);
          a2 = __builtin_amdgcn_mfma_f32_16x16x32_bf16(ah[kb], blo[kb], a2, 0, 0, 0);
          a3 = __builtin_amdgcn_mfma_f32_16x16x32_bf16(al[kb], bhi[kb], a3, 0, 0, 0);
        }
        f32x4 acc = a1 + a2 + a3;
        *(f32x4*)&sm.s.xh[v][l >> 4][c16][0] = acc;
        asm volatile("s_waitcnt lgkmcnt(0)" ::: "memory");
        __builtin_amdgcn_sched_barrier(0);
        if (l < 32) {
          #pragma unroll
          for (int g = 0; g < 4; ++g)
            sg[g] = sm.s.xh[v][bat >> 2][hl * 4 + g][bat & 3];
        }
      }

      if (l < 32) {
        float iv = fsigmoid(sg[0] + xwp[0]);
        float fv = fsigmoid(sg[1] + xwp[1]);
        float gv = ftanh   (sg[2] + xwp[2]);
        float ov = fsigmoid(sg[3] + xwp[3]);
        c = fv * c + iv * gv;
        float h = ov * ftanh(c);
        unsigned short hhi = f2bf(h);
        sm.s.hp[v][bat][hl] = hhi;
        sm.s.lp[v][bat][hl] = f2bf(h - bf2f(hhi));
      }
      asm volatile("s_waitcnt lgkmcnt(0)" ::: "memory");
      __builtin_amdgcn_sched_barrier(0);
      if (l < 8) {
        unsigned h0 = sm.s.hp[v][l][0], h1 = sm.s.hp[v][l][1];
        unsigned h2 = sm.s.hp[v][l][2], h3 = sm.s.hp[v][l][3];
        unsigned o0 = sm.s.lp[v][l][0], o1 = sm.s.lp[v][l][1];
        unsigned o2 = sm.s.lp[v][l][2], o3 = sm.s.lp[v][l][3];
        i32x2 rh, rl;
        rh.x = (int)((h1 << 16) | h0); rh.y = (int)((h3 << 16) | h2);
        rl.x = (int)((o1 << 16) | o0); rl.y = (int)((o3 << 16) | o2);
        int off = ((Wv >> 1) * 8 + l) * 8 + (Wv & 1) * 4;
        st8_cc(hbuf + (t & 1) * 2048 + off, rh);
        st8_cc(lbuf + (t & 1) * 2048 + off, rl);
        // hidden row segment (bat=l, cols Wv*4..+3) -> LLC BEFORE drain
        st8_cc(hidden + ((size_t)l * SEQ + t) * HID + Wv * 4, rh);
      }
      asm volatile("s_waitcnt vmcnt(0)" ::: "memory");
      __syncthreads();                          // barrier B
      if (tid == 0) st_int_cc(&flags[w], t + 1);
      if (l < 32) {
        int tn = (t + 1 < SEQ) ? t + 1 : t;
        #pragma unroll
        for (int g = 0; g < 4; ++g)
          xwp[g] = xW[((size_t)bat * SEQ + tn) * G4H + g * HID + H];
      }
    }
    // final publish: prove all WGs finished all SEQ steps
    if (bx == 0 && v == 0) {
      const int* fp = &flags[l & 7];
      int guard = 0;
      for (;;) {
        int f = ld_int_cc(fp);
        if (__all(f >= SEQ)) break;
        if (++guard > 30000) break;
      }
      if (l < 8) st_int_cc(&prog[l * 32], SEQ);
    }
    return;
  }

  // ================= GEMM tile (progress-gated) =================
  const int gb = bx - NWG;                 // 0..7999, t-major order
  int nb = gb % 125;
  int t2 = gb / 125;
  int bat = t2 & 7, tblk = t2 >> 3;
  int m0 = bat * 1024 + tblk * 128;
  int n0 = nb * 256;
  // xW lives in d_out tail (C rows >= 7929): wait for the full scan there
  int gate = (bat == 7 && tblk >= 5) ? SEQ : (tblk * 128 + 128);

  if (tid == 0) {
    const int* pp = &prog[(gb & 7) * 32];
    int guard = 0;
    while (ld_int_cc(pp) < gate) {
      #pragma unroll
      for (int s = 0; s < 4; ++s) __builtin_amdgcn_s_sleep(127);
      if (++guard > 4000) break;           // ~52 ms cap, way past scan end
    }
  }
  __syncthreads();

  const unsigned short* A = hidden;
  const int g  = v >> 2;                   // N-half (0/1)
  const int wq = v & 3;
  const int wr = wq >> 1, wc = wq & 1;
  f32x4 acc[4][4] = {};
  for (int kt = 0; kt < 4; ++kt) {
    int k0 = kt * 64;
    #pragma unroll
    for (int i = 0; i < 2; ++i) {
      int flat = tid + i * 512;
      int r = flat >> 3, cc = flat & 7;
      *(short8*)&sm.g.As[r * 72 + cc * 8] =
          *(const short8*)&A[(size_t)(m0 + r) * HID + k0 + cc * 8];
    }
    #pragma unroll
    for (int i = 0; i < 4; ++i) {
      int flat = tid + i * 512;
      int r = flat >> 3, cc = flat & 7;
      *(short8*)&sm.g.Bs[r * 72 + cc * 8] =
          *(const short8*)&BT[(size_t)(n0 + r) * HID + k0 + cc * 8];
    }
    __syncthreads();
    #pragma unroll
    for (int kb = 0; kb < 2; ++kb) {
      short8 af[4], bf[4];
      #pragma unroll
      for (int mi = 0; mi < 4; ++mi)
        af[mi] = *(const short8*)&sm.g.As[(wr * 64 + mi * 16 + (l & 15)) * 72 +
                                          kb * 32 + (l >> 4) * 8];
      #pragma unroll
      for (int ni = 0; ni < 4; ++ni)
        bf[ni] = *(const short8*)&sm.g.Bs[(g * 128 + wc * 64 + ni * 16 + (l & 15)) * 72 +
                                          kb * 32 + (l >> 4) * 8];
      #pragma unroll
      for (int mi = 0; mi < 4; ++mi)
        #pragma unroll
        for (int ni = 0; ni < 4; ++ni)
          acc[mi][ni] = __builtin_amdgcn_mfma_f32_16x16x32_bf16(
              af[mi], bf[ni], acc[mi][ni], 0, 0, 0);
    }
    __syncthreads();
  }
  #pragma unroll
  for (int ni = 0; ni < 4; ++ni) {
    int n = n0 + g * 128 + wc * 64 + ni * 16 + (l & 15);
    float bi = blin[n];
    #pragma unroll
    for (int mi = 0; mi < 4; ++mi) {
      int mbase = m0 + wr * 64 + mi * 16 + (l >> 4) * 4;
      #pragma unroll
      for (int q = 0; q < 4; ++q)
        st_f32_nt(&C[(size_t)(mbase + q) * VOCAB + n], acc[mi][ni][q] + bi);
    }
  }
}

extern "C" void kernel_launch(void* const* d_in, const int* in_sizes, int n_in,
                              void* d_out, int out_size, void* d_ws, size_t ws_size,
                              hipStream_t stream) {
  const int*   sent = (const int*)d_in[0];
  const float* wemb = (const float*)d_in[1];
  const float* W    = (const float*)d_in[2];
  const float* U    = (const float*)d_in[3];
  const float* bias = (const float*)d_in[4];
  const float* wlin = (const float*)d_in[5];
  const float* blin = (const float*)d_in[6];
  float* out = (float*)d_out;

  // xW (32 MB f32) at the TAIL of d_out; overlapping C rows gated at SEQ.
  float* xW = out + (262144000 - 8388608);

  char* ws = (char*)d_ws;
  unsigned short* BT     = (unsigned short*)ws;                        // 16,384,000 B
  unsigned short* hidden = (unsigned short*)(ws + 16384000);           //  4,194,304 B
  unsigned short* hbuf   = (unsigned short*)(ws + 16384000 + 4194304);           // 8 KB (pad 16K)
  unsigned short* lbuf   = (unsigned short*)(ws + 16384000 + 4194304 + 16384);   // 8 KB (pad 16K)
  int* flags             = (int*)(ws + 16384000 + 4194304 + 32768);              // 32 B
  int* prog              = (int*)(ws + 16384000 + 4194304 + 32768 + 131072);     // 1 KB, far away

  hipMemsetAsync(flags, 0, 64, stream);
  hipMemsetAsync(prog, 0, 1024, stream);
  k_embed_xw<<<2048, 256, 0, stream>>>(sent, wemb, W, bias, xW);
  k_transpose_w<<<dim3(500, 4), 256, 0, stream>>>(wlin, BT);
  k_fused<<<NWG + 8000, 512, 0, stream>>>(xW, U, hidden, hbuf, lbuf,
                                          flags, prog, BT, blin, out);
}